// Round 1
// baseline (402.059 us; speedup 1.0000x reference)
//
#include <hip/hip_runtime.h>

// WOQ int4-asym (tinygemm) linear: out[64,8192] = x @ dequant(w).T
// w int32 in [0,15]; dequant: (q - 8)*scale + zp, groups of 128 along K.
// Strategy: stream w global->VGPR in MFMA B-frag layout (read once, 256 MB
// -> HBM-bound floor ~42us), dequant in-register to bf16, 16x16x32 MFMA.
// x staged per-128k-group into LDS in frag-order bf16 (conflict-free b128).
// 16-way K-split across blocks, fp32 atomicAdd epilogue (out memset to 0).

#define OUT_F 8192
#define IN_F  8192
#define M_TOK 64
#define GROUP 128
#define BN    128            // n per block: 4 waves x 32
#define KSPLIT 16
#define KR    (IN_F / KSPLIT) // 512 k per block

typedef short  short8 __attribute__((ext_vector_type(8)));
typedef float  f32x4  __attribute__((ext_vector_type(4)));

__device__ __forceinline__ unsigned short f2bf(float f) {
    unsigned u = __float_as_uint(f);
    return (unsigned short)((u + 0x7FFFu + ((u >> 16) & 1u)) >> 16);
}

__global__ __launch_bounds__(256, 4)
void woq_linear_kernel(const float* __restrict__ x,
                       const int*   __restrict__ qw,
                       const float* __restrict__ sz,
                       float*       __restrict__ out) {
    __shared__ short lds_x[16 * 64 * 8];   // 16 chunks (ks,mi) x 64 lanes x 8 bf16 = 16 KB

    const int t    = threadIdx.x;
    const int lane = t & 63;
    const int wv   = t >> 6;          // wave 0..3
    const int n0   = blockIdx.x * BN; // n tile base
    const int k0   = blockIdx.y * KR; // k range base

    const int nlo  = lane & 15;
    const int quad = lane >> 4;
    const int kq8  = quad << 3;       // k offset of this lane's 8-elem run

    const int n1 = n0 + wv * 32 + nlo;
    const int n2 = n1 + 16;

    f32x4 acc[4][2];
#pragma unroll
    for (int mi = 0; mi < 4; ++mi)
#pragma unroll
        for (int ni = 0; ni < 2; ++ni)
            acc[mi][ni] = (f32x4){0.f, 0.f, 0.f, 0.f};

    for (int g = 0; g < KR / GROUP; ++g) {
        const int kg = k0 + g * GROUP;
        const int gg = kg >> 7;       // global group index

        // per-group scale / (zp - 8*scale) for this lane's two n values
        const float2 p1 = *(const float2*)(sz + ((size_t)gg * OUT_F + n1) * 2);
        const float2 p2 = *(const float2*)(sz + ((size_t)gg * OUT_F + n2) * 2);
        const float s1 = p1.x, c1 = fmaf(-8.f, p1.x, p1.y);
        const float s2 = p2.x, c2 = fmaf(-8.f, p2.x, p2.y);

        __syncthreads();
        // stage x[0:64][kg:kg+128] into LDS as bf16, frag order:
        // slot (chunk = ks*4+mi, l): x[mi*16 + (l&15)][ks*32 + (l>>4)*8 + j]
#pragma unroll
        for (int i = 0; i < 4; ++i) {
            int slot  = t + 256 * i;          // 0..1023
            int chunk = slot >> 6;
            int l     = slot & 63;
            int m     = ((chunk & 3) << 4) + (l & 15);
            int kk    = ((chunk >> 2) << 5) + ((l >> 4) << 3);
            const float4* p = (const float4*)(x + (size_t)m * IN_F + kg + kk);
            float4 v0 = p[0];
            float4 v1 = p[1];
            short8 bv;
            bv[0] = (short)f2bf(v0.x); bv[1] = (short)f2bf(v0.y);
            bv[2] = (short)f2bf(v0.z); bv[3] = (short)f2bf(v0.w);
            bv[4] = (short)f2bf(v1.x); bv[5] = (short)f2bf(v1.y);
            bv[6] = (short)f2bf(v1.z); bv[7] = (short)f2bf(v1.w);
            *(short8*)&lds_x[slot * 8] = bv;
        }
        __syncthreads();

#pragma unroll
        for (int ks = 0; ks < 4; ++ks) {
            const int k = kg + ks * 32;

            // --- B: weight stream (the HBM-critical loads) ---
            const int* q1p = qw + (size_t)n1 * IN_F + k + kq8;
            const int* q2p = qw + (size_t)n2 * IN_F + k + kq8;
            const int4 qa = *(const int4*)(q1p);
            const int4 qb = *(const int4*)(q1p + 4);
            const int4 qc = *(const int4*)(q2p);
            const int4 qd = *(const int4*)(q2p + 4);

            // --- A frags from LDS (conflict-free b128) ---
            short8 a[4];
#pragma unroll
            for (int mi = 0; mi < 4; ++mi)
                a[mi] = *(const short8*)&lds_x[((ks * 4 + mi) * 64 + lane) * 8];

            // --- dequant to bf16 ---
            short8 b1, b2;
            b1[0] = (short)f2bf(fmaf((float)qa.x, s1, c1));
            b1[1] = (short)f2bf(fmaf((float)qa.y, s1, c1));
            b1[2] = (short)f2bf(fmaf((float)qa.z, s1, c1));
            b1[3] = (short)f2bf(fmaf((float)qa.w, s1, c1));
            b1[4] = (short)f2bf(fmaf((float)qb.x, s1, c1));
            b1[5] = (short)f2bf(fmaf((float)qb.y, s1, c1));
            b1[6] = (short)f2bf(fmaf((float)qb.z, s1, c1));
            b1[7] = (short)f2bf(fmaf((float)qb.w, s1, c1));
            b2[0] = (short)f2bf(fmaf((float)qc.x, s2, c2));
            b2[1] = (short)f2bf(fmaf((float)qc.y, s2, c2));
            b2[2] = (short)f2bf(fmaf((float)qc.z, s2, c2));
            b2[3] = (short)f2bf(fmaf((float)qc.w, s2, c2));
            b2[4] = (short)f2bf(fmaf((float)qd.x, s2, c2));
            b2[5] = (short)f2bf(fmaf((float)qd.y, s2, c2));
            b2[6] = (short)f2bf(fmaf((float)qd.z, s2, c2));
            b2[7] = (short)f2bf(fmaf((float)qd.w, s2, c2));

#pragma unroll
            for (int mi = 0; mi < 4; ++mi) {
                acc[mi][0] = __builtin_amdgcn_mfma_f32_16x16x32_bf16(a[mi], b1, acc[mi][0], 0, 0, 0);
                acc[mi][1] = __builtin_amdgcn_mfma_f32_16x16x32_bf16(a[mi], b2, acc[mi][1], 0, 0, 0);
            }
        }
    }

    // epilogue: C/D layout col = lane&15, row = quad*4 + r
#pragma unroll
    for (int mi = 0; mi < 4; ++mi) {
#pragma unroll
        for (int ni = 0; ni < 2; ++ni) {
            const int n = n0 + wv * 32 + ni * 16 + nlo;
#pragma unroll
            for (int r = 0; r < 4; ++r) {
                const int m = mi * 16 + quad * 4 + r;
                atomicAdd(out + (size_t)m * OUT_F + n, acc[mi][ni][r]);
            }
        }
    }
}

extern "C" void kernel_launch(void* const* d_in, const int* in_sizes, int n_in,
                              void* d_out, int out_size, void* d_ws, size_t ws_size,
                              hipStream_t stream) {
    const float* x  = (const float*)d_in[0];
    const int*   qw = (const int*)d_in[1];
    const float* sz = (const float*)d_in[2];
    float* out = (float*)d_out;

    // zero accumulator target (harness poisons d_out before every launch)
    hipMemsetAsync(d_out, 0, (size_t)out_size * sizeof(float), stream);

    dim3 grid(OUT_F / BN, KSPLIT);
    woq_linear_kernel<<<grid, 256, 0, stream>>>(x, qw, sz, out);
}

// Round 2
// 389.791 us; speedup vs baseline: 1.0315x; 1.0315x over previous
//
#include <hip/hip_runtime.h>

// WOQ int4-asym (tinygemm) linear: out[64,8192] = x @ dequant(w).T
// w int32 in [0,15]; dequant: (q - 8)*scale + zp, groups of 128 along K.
// R2: replace 8.4M-atomicAdd epilogue (suspected 300+us serialization at the
// coherence point) with K-split partials in d_ws + float4 reduction kernel.
// Also cheaper bf16 pack (round-half-up, pair-packed) to cut VALU + regs.
// Weight stream stays global->VGPR in MFMA B-frag layout (256 MB read once).

#define OUT_F 8192
#define IN_F  8192
#define M_TOK 64
#define GROUP 128
#define BN    128             // n per block: 4 waves x 32
#define KSPLIT 16
#define KR    (IN_F / KSPLIT) // 512 k per block

typedef short short8 __attribute__((ext_vector_type(8)));
typedef float f32x4  __attribute__((ext_vector_type(4)));
typedef int   int4v  __attribute__((ext_vector_type(4)));

// pack two fp32 -> two bf16 (round-half-up) in one int
__device__ __forceinline__ int pack_bf2(float lo, float hi) {
    unsigned ul = __float_as_uint(lo) + 0x8000u;
    unsigned uh = __float_as_uint(hi) + 0x8000u;
    return (int)((ul >> 16) | (uh & 0xFFFF0000u));
}

template <bool ATOMIC>
__global__ __launch_bounds__(256, 4)
void woq_gemm(const float* __restrict__ x,
              const int*   __restrict__ qw,
              const float* __restrict__ sz,
              float*       __restrict__ outp) {
    __shared__ int lds_x[16 * 64 * 4];   // 16 chunks x 64 lanes x 16 B = 16 KB

    const int t    = threadIdx.x;
    const int lane = t & 63;
    const int wv   = t >> 6;          // wave 0..3
    const int n0   = blockIdx.x * BN; // n tile base
    const int k0   = blockIdx.y * KR; // k range base

    const int nlo  = lane & 15;
    const int quad = lane >> 4;
    const int kq8  = quad << 3;       // k offset of this lane's 8-int run

    const int n1 = n0 + wv * 32 + nlo;
    const int n2 = n1 + 16;

    f32x4 acc[4][2];
#pragma unroll
    for (int mi = 0; mi < 4; ++mi)
#pragma unroll
        for (int ni = 0; ni < 2; ++ni)
            acc[mi][ni] = (f32x4){0.f, 0.f, 0.f, 0.f};

    for (int g = 0; g < KR / GROUP; ++g) {
        const int kg = k0 + g * GROUP;
        const int gg = kg >> 7;       // global group index

        // per-group scale / (zp - 8*scale) for this lane's two n values
        const float2 p1 = *(const float2*)(sz + ((size_t)gg * OUT_F + n1) * 2);
        const float2 p2 = *(const float2*)(sz + ((size_t)gg * OUT_F + n2) * 2);
        const float s1 = p1.x, c1 = fmaf(-8.f, p1.x, p1.y);
        const float s2 = p2.x, c2 = fmaf(-8.f, p2.x, p2.y);

        __syncthreads();
        // stage x[0:64][kg:kg+128] as bf16 in frag order:
        // slot (chunk = ks*4+mi, l): x[mi*16 + (l&15)][ks*32 + (l>>4)*8 + j]
#pragma unroll
        for (int i = 0; i < 4; ++i) {
            int slot  = t + 256 * i;          // 0..1023
            int chunk = slot >> 6;
            int l     = slot & 63;
            int m     = ((chunk & 3) << 4) + (l & 15);
            int kk    = ((chunk >> 2) << 5) + ((l >> 4) << 3);
            const float4* p = (const float4*)(x + (size_t)m * IN_F + kg + kk);
            float4 v0 = p[0];
            float4 v1 = p[1];
            int4v bv;
            bv.x = pack_bf2(v0.x, v0.y);
            bv.y = pack_bf2(v0.z, v0.w);
            bv.z = pack_bf2(v1.x, v1.y);
            bv.w = pack_bf2(v1.z, v1.w);
            *(int4v*)&lds_x[slot * 4] = bv;
        }
        __syncthreads();

#pragma unroll
        for (int ks = 0; ks < 4; ++ks) {
            const int k = kg + ks * 32;

            // --- B: weight stream (the HBM-critical loads), issue all early ---
            const int* q1p = qw + (size_t)n1 * IN_F + k + kq8;
            const int* q2p = qw + (size_t)n2 * IN_F + k + kq8;
            const int4 qa = *(const int4*)(q1p);
            const int4 qb = *(const int4*)(q1p + 4);
            const int4 qc = *(const int4*)(q2p);
            const int4 qd = *(const int4*)(q2p + 4);

            // --- A frags from LDS (conflict-free b128) ---
            short8 a[4];
#pragma unroll
            for (int mi = 0; mi < 4; ++mi)
                a[mi] = *(const short8*)&lds_x[((ks * 4 + mi) * 64 + lane) * 4];

            // --- dequant to bf16 (pair-packed) ---
            int4v b1i, b2i;
            b1i.x = pack_bf2(fmaf((float)qa.x, s1, c1), fmaf((float)qa.y, s1, c1));
            b1i.y = pack_bf2(fmaf((float)qa.z, s1, c1), fmaf((float)qa.w, s1, c1));
            b1i.z = pack_bf2(fmaf((float)qb.x, s1, c1), fmaf((float)qb.y, s1, c1));
            b1i.w = pack_bf2(fmaf((float)qb.z, s1, c1), fmaf((float)qb.w, s1, c1));
            short8 b1 = __builtin_bit_cast(short8, b1i);
#pragma unroll
            for (int mi = 0; mi < 4; ++mi)
                acc[mi][0] = __builtin_amdgcn_mfma_f32_16x16x32_bf16(a[mi], b1, acc[mi][0], 0, 0, 0);

            b2i.x = pack_bf2(fmaf((float)qc.x, s2, c2), fmaf((float)qc.y, s2, c2));
            b2i.y = pack_bf2(fmaf((float)qc.z, s2, c2), fmaf((float)qc.w, s2, c2));
            b2i.z = pack_bf2(fmaf((float)qd.x, s2, c2), fmaf((float)qd.y, s2, c2));
            b2i.w = pack_bf2(fmaf((float)qd.z, s2, c2), fmaf((float)qd.w, s2, c2));
            short8 b2 = __builtin_bit_cast(short8, b2i);
#pragma unroll
            for (int mi = 0; mi < 4; ++mi)
                acc[mi][1] = __builtin_amdgcn_mfma_f32_16x16x32_bf16(a[mi], b2, acc[mi][1], 0, 0, 0);
        }
    }

    // epilogue: C/D layout col = lane&15, row = quad*4 + r
    float* dst = ATOMIC ? outp : outp + (size_t)blockIdx.y * (M_TOK * OUT_F);
#pragma unroll
    for (int mi = 0; mi < 4; ++mi) {
#pragma unroll
        for (int ni = 0; ni < 2; ++ni) {
            const int n = n0 + wv * 32 + ni * 16 + nlo;
#pragma unroll
            for (int r = 0; r < 4; ++r) {
                const int m = mi * 16 + quad * 4 + r;
                if (ATOMIC)
                    atomicAdd(dst + (size_t)m * OUT_F + n, acc[mi][ni][r]);
                else
                    dst[(size_t)m * OUT_F + n] = acc[mi][ni][r];
            }
        }
    }
}

__global__ __launch_bounds__(256)
void woq_reduce(const float* __restrict__ part, float* __restrict__ out) {
    const int i = (blockIdx.x * 256 + threadIdx.x) * 4;
    const size_t stride = (size_t)M_TOK * OUT_F;
    float4 s = *(const float4*)(part + i);
#pragma unroll
    for (int k = 1; k < KSPLIT; ++k) {
        float4 v = *(const float4*)(part + (size_t)k * stride + i);
        s.x += v.x; s.y += v.y; s.z += v.z; s.w += v.w;
    }
    *(float4*)(out + i) = s;
}

extern "C" void kernel_launch(void* const* d_in, const int* in_sizes, int n_in,
                              void* d_out, int out_size, void* d_ws, size_t ws_size,
                              hipStream_t stream) {
    const float* x  = (const float*)d_in[0];
    const int*   qw = (const int*)d_in[1];
    const float* sz = (const float*)d_in[2];
    float* out = (float*)d_out;

    dim3 grid(OUT_F / BN, KSPLIT);
    const size_t need = (size_t)KSPLIT * M_TOK * OUT_F * sizeof(float);

    if (ws_size >= need) {
        float* part = (float*)d_ws;
        woq_gemm<false><<<grid, 256, 0, stream>>>(x, qw, sz, part);
        woq_reduce<<<(M_TOK * OUT_F) / (256 * 4), 256, 0, stream>>>(part, out);
    } else {
        hipMemsetAsync(d_out, 0, (size_t)out_size * sizeof(float), stream);
        woq_gemm<true><<<grid, 256, 0, stream>>>(x, qw, sz, out);
    }
}